// Round 3
// baseline (582.733 us; speedup 1.0000x reference)
//
#include <hip/hip_runtime.h>
#include <hip/hip_bf16.h>
#include <stdint.h>

typedef __attribute__((ext_vector_type(8))) short short8;
typedef __attribute__((ext_vector_type(4))) float floatx4;

#define MODE_QKV    0  // merged projections: bf16 out, +bias, q/v transposed, k normal
#define MODE_SCORES 2  // f32 out, *alpha, no bias, batched
#define MODE_ATT    3  // bf16 out, no bias, batched
#define MODE_OUT    4  // f32 out, +bias, normal

__device__ __forceinline__ unsigned short f2bf(float f) {
    union { float f; unsigned int u; } x; x.f = f;
    unsigned int u = x.u + 0x7FFFu + ((x.u >> 16) & 1u);  // RNE
    return (unsigned short)(u >> 16);
}

__device__ __forceinline__ void gload_lds16(const void* g, void* lds) {
    __builtin_amdgcn_global_load_lds(
        (const __attribute__((address_space(1))) unsigned int*)g,
        (__attribute__((address_space(3))) unsigned int*)lds,
        16, 0, 0);
}

// C[m,n] = alpha * sum_k A[m,k]*B[n,k] (+ bias[n])   -- NT GEMM, ld=1024
// 1D grid, XCD-aware decode (hardware round-robins consecutive ids over 8 XCDs):
//  QKV/OUT: XCD j owns rows y%8==j for all col-blocks (A-tile L2 reuse)
//  batched: XCD j owns batches z%8==j (whole batch A+B fits one L2)
// MODE_QKV: grid 3072; col segment 0/1/2 selects activation (A+idx*16M),
//  weight (B+idx*1M), bias{1,2,3}, and store layout (qT / kp / vT contiguous at Cout).
template<int MODE>
__global__ __launch_bounds__(256) void gemm_nt(
    const __hip_bfloat16* __restrict__ A,
    const __hip_bfloat16* __restrict__ Bm,
    const float* __restrict__ bias,
    const float* __restrict__ bias2,
    const float* __restrict__ bias3,
    void* __restrict__ Cout,
    int K, long sA, long sB, long sC, float alpha)
{
    __shared__ short As[128 * 64];
    __shared__ short Bs[128 * 64];

    const int tid  = threadIdx.x;
    const int wid  = tid >> 6;
    const int lane = tid & 63;

    const int id  = blockIdx.x;
    const int xcd = id & 7;
    const int s   = id >> 3;
    int bx, by, bz;
    if (MODE == MODE_SCORES || MODE == MODE_ATT) {
        bz = xcd + ((s >> 6) << 3);   // batches {j, j+8} on XCD j
        by = (s >> 3) & 7;
        bx = s & 7;
    } else {
        bz = 0;
        bx = s >> 4;                  // QKV: 0..23, OUT: 0..7
        by = ((s & 15) << 3) | xcd;   // y%8 == xcd
    }
    const int row0 = by * 128;
    const int col0 = bx * 128;
    const int seg  = (MODE == MODE_QKV) ? (bx >> 3) : 0;   // 0=q 1=k 2=v

    const __hip_bfloat16* Ab;
    const __hip_bfloat16* Bb;
    int colA0;                         // col offset within segment
    if (MODE == MODE_QKV) {
        Ab = A  + ((size_t)seg << 24);         // activations 16M elems apart
        Bb = Bm + ((size_t)seg << 20);         // weights 1M elems apart
        colA0 = col0 & 1023;
    } else {
        Ab = A  + (size_t)bz * sA;
        Bb = Bm + (size_t)bz * sB;
        colA0 = col0;
    }

    floatx4 acc[4][4];
#pragma unroll
    for (int i = 0; i < 4; i++)
#pragma unroll
        for (int j = 0; j < 4; j++) acc[i][j] = (floatx4){0.f, 0.f, 0.f, 0.f};

    const int l7   = lane & 7;
    const int l3   = lane >> 3;            // 0..7
    const int cblk = ((l7 ^ l3) << 3);     // swizzled k-block (elements)
    const int wm   = wid >> 1, wn = wid & 1;
    const int l15  = lane & 15, quad = lane >> 4;

    for (int k0 = 0; k0 < K; k0 += 64) {
        __syncthreads();   // previous tile's compute done before overwrite
#pragma unroll
        for (int i = 0; i < 4; i++) {
            const int c = wid * 4 + i;        // chunk 0..15, 8 rows each
            const int r = c * 8 + l3;
            gload_lds16(Ab + (size_t)(row0 + r) * 1024 + k0 + cblk, As + c * 512);
            gload_lds16(Bb + (size_t)(colA0 + r) * 1024 + k0 + cblk, Bs + c * 512);
        }
        __syncthreads();   // staging visible
#pragma unroll
        for (int ks = 0; ks < 2; ks++) {
            short8 af[4], bfr[4];
            const int kb = (((ks * 4 + quad) ^ l7) << 3);   // row&7 == l7 for all tiles
#pragma unroll
            for (int t = 0; t < 4; t++) {
                af[t]  = *(const short8*)&As[(wm * 64 + t * 16 + l15) * 64 + kb];
                bfr[t] = *(const short8*)&Bs[(wn * 64 + t * 16 + l15) * 64 + kb];
            }
#pragma unroll
            for (int mt = 0; mt < 4; mt++)
#pragma unroll
                for (int nt = 0; nt < 4; nt++)
                    acc[mt][nt] = __builtin_amdgcn_mfma_f32_16x16x32_bf16(
                        af[mt], bfr[nt], acc[mt][nt], 0, 0, 0);
        }
    }

    // epilogue: C/D layout col=lane&15, row=quad*4+reg  [m89/m91-verified]
#pragma unroll
    for (int nt = 0; nt < 4; nt++) {
        const int col = col0 + wn * 64 + nt * 16 + l15;
        const int cl  = col & 1023;     // col within segment (QKV)
        float bv = 0.f;
        if (MODE == MODE_QKV) {
            const float* bp = (seg == 0) ? bias : ((seg == 1) ? bias2 : bias3);
            bv = bp[cl];
        } else if (MODE == MODE_OUT) {
            bv = bias[col];
        }
#pragma unroll
        for (int mt = 0; mt < 4; mt++) {
            const int rbase = row0 + wm * 64 + mt * 16 + quad * 4;
#pragma unroll
            for (int r = 0; r < 4; r++) {
                const int m = rbase + r;
                float v = acc[mt][nt][r];
                if (MODE == MODE_SCORES) v *= alpha;
                v += bv;
                if (MODE == MODE_SCORES) {
                    ((float*)Cout)[(size_t)bz * sC + (size_t)m * 1024 + col] = v;
                } else if (MODE == MODE_OUT) {
                    ((float*)Cout)[(size_t)m * 1024 + col] = v;
                } else if (MODE == MODE_ATT) {
                    ((unsigned short*)Cout)[(size_t)bz * sC + (size_t)m * 1024 + col] = f2bf(v);
                } else { // MODE_QKV
                    unsigned short* o = (unsigned short*)Cout + ((size_t)seg << 24);
                    if (seg == 1) {       // kp: normal [m, cl]
                        o[(size_t)m * 1024 + cl] = f2bf(v);
                    } else {              // qT / vT: [b=m>>10, cl, m&1023]
                        o[((size_t)(m >> 10) << 20) + (size_t)cl * 1024 + (m & 1023)] = f2bf(v);
                    }
                }
            }
        }
    }
}

// one wave per 1024-float row; 4 rows per 256-thread block
__global__ __launch_bounds__(256) void softmax_rows(
    const float* __restrict__ S, unsigned short* __restrict__ A)
{
    const int row  = blockIdx.x * 4 + (threadIdx.x >> 6);
    const int lane = threadIdx.x & 63;
    const float4* p = (const float4*)(S + (size_t)row * 1024);
    float4 v[4];
    float mx = -3.0e38f;
#pragma unroll
    for (int i = 0; i < 4; i++) {
        v[i] = p[lane + i * 64];
        mx = fmaxf(mx, fmaxf(fmaxf(v[i].x, v[i].y), fmaxf(v[i].z, v[i].w)));
    }
#pragma unroll
    for (int off = 32; off >= 1; off >>= 1) mx = fmaxf(mx, __shfl_xor(mx, off, 64));
    float e[16], sum = 0.f;
#pragma unroll
    for (int i = 0; i < 4; i++) {
        e[i*4+0] = __expf(v[i].x - mx); e[i*4+1] = __expf(v[i].y - mx);
        e[i*4+2] = __expf(v[i].z - mx); e[i*4+3] = __expf(v[i].w - mx);
        sum += e[i*4+0] + e[i*4+1] + e[i*4+2] + e[i*4+3];
    }
#pragma unroll
    for (int off = 32; off >= 1; off >>= 1) sum += __shfl_xor(sum, off, 64);
    const float inv = 1.0f / sum;
    ushort4* out = (ushort4*)(A + (size_t)row * 1024);
#pragma unroll
    for (int i = 0; i < 4; i++) {
        ushort4 o;
        o.x = f2bf(e[i*4+0] * inv); o.y = f2bf(e[i*4+1] * inv);
        o.z = f2bf(e[i*4+2] * inv); o.w = f2bf(e[i*4+3] * inv);
        out[lane + i * 64] = o;
    }
}

// f32->bf16 for q,k,v,Wq,Wk,Wv,Wo into the contiguous bf16 arena at ws+0.
// 8 float4 per thread (32KB/block), 16B stores.
__global__ __launch_bounds__(256) void cvt_all(
    const float* __restrict__ q, const float* __restrict__ k, const float* __restrict__ v,
    const float* __restrict__ wq, const float* __restrict__ wk,
    const float* __restrict__ wv, const float* __restrict__ wo,
    unsigned short* __restrict__ dst)
{
    const int id = blockIdx.x, t = threadIdx.x;
    const float* src; int local; size_t dbase;  // dbase in ushort8 units
    if      (id < 2048) { src = q;  local = id;        dbase = 0; }
    else if (id < 4096) { src = k;  local = id - 2048; dbase = (size_t)16 << 20 >> 3; }
    else if (id < 6144) { src = v;  local = id - 4096; dbase = (size_t)32 << 20 >> 3; }
    else if (id < 6272) { src = wq; local = id - 6144; dbase = (size_t)48 << 20 >> 3; }
    else if (id < 6400) { src = wk; local = id - 6272; dbase = (size_t)49 << 20 >> 3; }
    else if (id < 6528) { src = wv; local = id - 6400; dbase = (size_t)50 << 20 >> 3; }
    else                { src = wo; local = id - 6528; dbase = (size_t)51 << 20 >> 3; }
    const float4* s4 = (const float4*)src + (size_t)local * 2048;
    short8* d8 = (short8*)dst + dbase + (size_t)local * 1024;
#pragma unroll
    for (int j = 0; j < 4; j++) {
        const float4 a = s4[j * 512 + 2 * t];
        const float4 b = s4[j * 512 + 2 * t + 1];
        short8 o;
        o[0] = (short)f2bf(a.x); o[1] = (short)f2bf(a.y);
        o[2] = (short)f2bf(a.z); o[3] = (short)f2bf(a.w);
        o[4] = (short)f2bf(b.x); o[5] = (short)f2bf(b.y);
        o[6] = (short)f2bf(b.z); o[7] = (short)f2bf(b.w);
        d8[j * 256 + t] = o;
    }
}

extern "C" void kernel_launch(void* const* d_in, const int* in_sizes, int n_in,
                              void* d_out, int out_size, void* d_ws, size_t ws_size,
                              hipStream_t stream) {
    const float* query = (const float*)d_in[0];
    const float* key   = (const float*)d_in[1];
    const float* value = (const float*)d_in[2];
    const float* Wq = (const float*)d_in[3];  const float* bq = (const float*)d_in[4];
    const float* Wk = (const float*)d_in[5];  const float* bk = (const float*)d_in[6];
    const float* Wv = (const float*)d_in[7];  const float* bv = (const float*)d_in[8];
    const float* Wo = (const float*)d_in[9];  const float* bo = (const float*)d_in[10];

    char* ws = (char*)d_ws;
    const size_t MB = 1ull << 20;
    unsigned short* qbf = (unsigned short*)(ws + 0   * MB);   // 32MB  (qbf|kbf|vbf contiguous)
    unsigned short* wqb = (unsigned short*)(ws + 96  * MB);   // 2MB   (wqb|wkb|wvb|wob contiguous)
    unsigned short* qT  = (unsigned short*)(ws + 104 * MB);   // 32MB  (qT|kp|vT contiguous)
    float*          sc  = (float*)(ws + 0 * MB);              // overlay qbf+kbf, 64MB
    unsigned short* att = (unsigned short*)(ws + 64 * MB);    // overlay vbf, 32MB
    unsigned short* kp  = (unsigned short*)(ws + 136 * MB);
    unsigned short* vT  = (unsigned short*)(ws + 168 * MB);
    unsigned short* ob  = (unsigned short*)(ws + 104 * MB);   // overlay qT, 32MB

    const long S1M = 1 << 20;
    dim3 blk(256);

    cvt_all<<<6656, blk, 0, stream>>>(query, key, value, Wq, Wk, Wv, Wo, qbf);

    // merged q/k/v projections: 3 x (M=16384, N=1024, K=1024), grid 3072
    gemm_nt<MODE_QKV><<<3072, blk, 0, stream>>>(
        (const __hip_bfloat16*)qbf, (const __hip_bfloat16*)wqb, bq, bk, bv,
        qT, 1024, 0, 0, 0, 1.f);

    // scores: per-batch 1024x1024, batch pinned to XCD
    gemm_nt<MODE_SCORES><<<1024, blk, 0, stream>>>(
        (const __hip_bfloat16*)qT, (const __hip_bfloat16*)kp, nullptr, nullptr, nullptr,
        sc, 1024, S1M, S1M, S1M, 0.03125f);

    softmax_rows<<<4096, blk, 0, stream>>>(sc, att);

    gemm_nt<MODE_ATT><<<1024, blk, 0, stream>>>(
        (const __hip_bfloat16*)att, (const __hip_bfloat16*)vT, nullptr, nullptr, nullptr,
        ob, 1024, S1M, S1M, S1M, 1.f);

    gemm_nt<MODE_OUT><<<1024, blk, 0, stream>>>(
        (const __hip_bfloat16*)ob, (const __hip_bfloat16*)wqb + (3ull << 20), bo, nullptr, nullptr,
        d_out, 1024, 0, 0, 0, 1.f);
}